// Round 5
// baseline (691.395 us; speedup 1.0000x reference)
//
#include <hip/hip_runtime.h>
#include <hip/hip_bf16.h>
#include <stdint.h>

// Problem constants
#define M_TOT 4096   // 2 * 2048
#define K_DIM 4096   // IN_FEATURES
#define N_DIM 16384  // OUT_FEATURES

typedef __attribute__((ext_vector_type(8))) short bf16x8;  // 8 bf16 = 4 VGPRs
typedef __attribute__((ext_vector_type(4))) float f32x4;   // MFMA 16x16 acc

__device__ __forceinline__ unsigned short f2bf(float f) {
  union { float f; unsigned u; } v; v.f = f;
  unsigned r = v.u + 0x7fffu + ((v.u >> 16) & 1u);  // RNE
  return (unsigned short)(r >> 16);
}

__global__ void cvt_f32_bf16_k(const float4* __restrict__ src,
                               ushort4* __restrict__ dst, int n4) {
  int stride = gridDim.x * blockDim.x;
  for (int i = blockIdx.x * blockDim.x + threadIdx.x; i < n4; i += stride) {
    float4 v = src[i];
    ushort4 o;
    o.x = f2bf(v.x); o.y = f2bf(v.y); o.z = f2bf(v.z); o.w = f2bf(v.w);
    dst[i] = o;
  }
}

__global__ void cvt_i32_bf16_k(const int4* __restrict__ src,
                               ushort4* __restrict__ dst, int n4) {
  int stride = gridDim.x * blockDim.x;
  for (int i = blockIdx.x * blockDim.x + threadIdx.x; i < n4; i += stride) {
    int4 v = src[i];
    ushort4 o;
    o.x = f2bf((float)v.x); o.y = f2bf((float)v.y);
    o.z = f2bf((float)v.z); o.w = f2bf((float)v.w);
    dst[i] = o;
  }
}

__device__ __forceinline__ void gload16(const void* g, void* l) {
  __builtin_amdgcn_global_load_lds(
      (__attribute__((address_space(1))) void*)(g),
      (__attribute__((address_space(3))) void*)(l),
      16, 0, 0);
}

// XOR-swizzle involution on byte offsets within a 16KB block ([256][32] bf16,
// 64B rows). XORs bits 4-6 with bits 7-9: bits 7-9 untouched -> involution.
// Verified round 2 with the 16x16 fragment read pattern: SQ_LDS_BANK_CONFLICT==0.
#define SWZ(o) ((o) ^ ((((o) >> 7) & 7) << 4))

#define MFMA_B16(a, b, c) __builtin_amdgcn_mfma_f32_16x16x32_bf16(a, b, c, 0, 0, 0)

// 256x256 tile, BK=64, 8 waves (2M x 4N), 4 phases/K-tile, counted vmcnt(4),
// setprio around MFMA, XOR-swizzled LDS, hoisted ds_read offsets, uniform-base
// staging addresses (scalar-pipe kb advance).
// LDS (bytes): buf b at b*65536; A slice s at +s*16384; B slice s at +32768+s*16384.
__global__ __launch_bounds__(512, 2)
void gemm_8phase(const ushort* __restrict__ A, const ushort* __restrict__ W,
                 const float* __restrict__ scale, const float* __restrict__ bias,
                 float* __restrict__ C) {
  __shared__ __align__(16) ushort lds[65536];  // 128 KiB
  char* lbase = (char*)lds;

  const int tid  = threadIdx.x;
  const int lane = tid & 63;
  const int wave = tid >> 6;
  const int wm   = wave >> 2;  // 0..1
  const int wn   = wave & 3;   // 0..3
  const int r    = lane & 15;
  const int kq16 = (lane >> 4) << 4;  // kq*16 bytes

  // XCD column-chunked mapping (round-3 verified: FETCH halved): bid%8 = XCD,
  // each XCD owns 8 tn columns, tm fastest -> B panel L2-resident per XCD.
  const int bid = blockIdx.x;
  const int xcd = bid & 7;
  const int ic  = bid >> 3;                 // 0..127
  const int tn  = (xcd << 3) | (ic >> 4);   // 0..63
  const int tm  = ic & 15;                  // 0..15
  const int row0 = tm * 256;
  const int col0 = tn * 256;

  // Staging: per-thread global coords; linear LDS dest off holds logical SWZ(off).
  int s_row0, s_col0, s_row1, s_col1;
  {
    int l0 = SWZ(tid * 16);
    int l1 = SWZ(8192 + tid * 16);
    s_row0 = l0 >> 6; s_col0 = (l0 & 63) >> 1;
    s_row1 = l1 >> 6; s_col1 = (l1 & 63) >> 1;
  }
  // per-thread invariant element offsets within a panel
  const size_t tOff0 = (size_t)s_row0 * K_DIM + s_col0;
  const size_t tOff1 = (size_t)s_row1 * K_DIM + s_col1;
  // wave-uniform panel bases (kb added per call, scalar)
  const ushort* Arow = A + (size_t)row0 * K_DIM;
  const ushort* Wrow = W + (size_t)col0 * K_DIM;

  // Gbase must be wave-uniform; per-thread part lives in tOff0/tOff1.
  auto STAGE = [&](const ushort* Gbase, int blkB) {
    gload16(Gbase + tOff0, lbase + blkB + (wave << 10));
    gload16(Gbase + tOff1, lbase + blkB + 8192 + (wave << 10));
  };

  // Hoisted, loop-invariant swizzled fragment offsets (within a 16KB slice).
  int offA[8], offB[4];
#pragma unroll
  for (int q = 0; q < 8; ++q)
    offA[q] = SWZ(((wm * 128 + q * 16 + r) << 6) + kq16);
#pragma unroll
  for (int q = 0; q < 4; ++q)
    offB[q] = SWZ(((wn * 64 + q * 16 + r) << 6) + kq16);

  f32x4 acc[8][4];
#pragma unroll
  for (int i = 0; i < 8; ++i)
#pragma unroll
    for (int j = 0; j < 4; ++j)
      acc[i][j] = (f32x4){0.f, 0.f, 0.f, 0.f};

  // Prologue: T0 all 4 blocks + T1 slice-0 blocks
  STAGE(Arow,      0);
  STAGE(Wrow,      32768);
  STAGE(Arow + 32, 16384);
  STAGE(Wrow + 32, 49152);
  STAGE(Arow + 64, 65536);
  STAGE(Wrow + 64, 98304);
  asm volatile("s_waitcnt vmcnt(4)" ::: "memory");  // T0 resident, T1-s0 in flight
  __builtin_amdgcn_s_barrier();

  bf16x8 a[4], b[4];

  for (int t = 0; t < 64; ++t) {
    const int cur  = t & 1;
    const int curB = cur << 16;
    const int nxtB = (cur ^ 1) << 16;
    const int kb1  = ((t + 1 < 64) ? t + 1 : 63) * 64;  // clamp keeps vmcnt uniform
    const int kb2  = ((t + 2 < 64) ? t + 2 : 63) * 64;

    // ---- P1: ks0 x m-half0 ----
#pragma unroll
    for (int q = 0; q < 4; ++q)
      a[q] = *(const bf16x8*)(lbase + curB + offA[q]);
#pragma unroll
    for (int q = 0; q < 4; ++q)
      b[q] = *(const bf16x8*)(lbase + curB + 32768 + offB[q]);
    STAGE(Arow + kb1 + 32, nxtB + 16384);  // T(t+1) A s1
    __builtin_amdgcn_s_barrier();
    __builtin_amdgcn_s_setprio(1);
#pragma unroll
    for (int mi = 0; mi < 4; ++mi)
#pragma unroll
      for (int ni = 0; ni < 4; ++ni)
        acc[mi][ni] = MFMA_B16(a[mi], b[ni], acc[mi][ni]);
    __builtin_amdgcn_s_setprio(0);
    __builtin_amdgcn_s_barrier();

    // ---- P2: ks0 x m-half1 (reuse b) ----
#pragma unroll
    for (int q = 0; q < 4; ++q)
      a[q] = *(const bf16x8*)(lbase + curB + offA[4 + q]);
    STAGE(Wrow + kb1 + 32, nxtB + 49152);  // T(t+1) B s1
    __builtin_amdgcn_s_barrier();
    __builtin_amdgcn_s_setprio(1);
#pragma unroll
    for (int mi = 0; mi < 4; ++mi)
#pragma unroll
      for (int ni = 0; ni < 4; ++ni)
        acc[4 + mi][ni] = MFMA_B16(a[mi], b[ni], acc[4 + mi][ni]);
    __builtin_amdgcn_s_setprio(0);
    __builtin_amdgcn_s_barrier();

    // ---- P3: ks1 x m-half0 ----
#pragma unroll
    for (int q = 0; q < 4; ++q)
      a[q] = *(const bf16x8*)(lbase + curB + 16384 + offA[q]);
#pragma unroll
    for (int q = 0; q < 4; ++q)
      b[q] = *(const bf16x8*)(lbase + curB + 49152 + offB[q]);
    STAGE(Arow + kb2, curB);  // T(t+2) A s0 -> dead region
    __builtin_amdgcn_s_barrier();
    __builtin_amdgcn_s_setprio(1);
#pragma unroll
    for (int mi = 0; mi < 4; ++mi)
#pragma unroll
      for (int ni = 0; ni < 4; ++ni)
        acc[mi][ni] = MFMA_B16(a[mi], b[ni], acc[mi][ni]);
    __builtin_amdgcn_s_setprio(0);
    __builtin_amdgcn_s_barrier();

    // ---- P4: ks1 x m-half1 (reuse b) ----
#pragma unroll
    for (int q = 0; q < 4; ++q)
      a[q] = *(const bf16x8*)(lbase + curB + 16384 + offA[4 + q]);
    STAGE(Wrow + kb2, curB + 32768);  // T(t+2) B s0 -> dead region
    __builtin_amdgcn_s_barrier();
    __builtin_amdgcn_s_setprio(1);
#pragma unroll
    for (int mi = 0; mi < 4; ++mi)
#pragma unroll
      for (int ni = 0; ni < 4; ++ni)
        acc[4 + mi][ni] = MFMA_B16(a[mi], b[ni], acc[4 + mi][ni]);
    __builtin_amdgcn_s_setprio(0);
    // counted wait: <=4 outstanding (= T(t+2) s0); T(t+1) fully landed
    asm volatile("s_waitcnt vmcnt(4)" ::: "memory");
    __builtin_amdgcn_s_barrier();
  }

  // don't retire with in-flight LDS writes
  asm volatile("s_waitcnt vmcnt(0)" ::: "memory");

  // Epilogue: C/D layout col=lane&15, row=(lane>>4)*4+reg (verified rounds 1-2)
  const int kq = kq16 >> 4;
#pragma unroll
  for (int ni = 0; ni < 4; ++ni) {
    const int col = col0 + wn * 64 + ni * 16 + r;
    const float sc = scale[col];
    const float bv = bias[col];
#pragma unroll
    for (int mi = 0; mi < 8; ++mi) {
      const int rowb = row0 + wm * 128 + mi * 16 + kq * 4;
#pragma unroll
      for (int q = 0; q < 4; ++q)
        C[(size_t)(rowb + q) * N_DIM + col] = acc[mi][ni][q] * sc + bv;
    }
  }
}

extern "C" void kernel_launch(void* const* d_in, const int* in_sizes, int n_in,
                              void* d_out, int out_size, void* d_ws, size_t ws_size,
                              hipStream_t stream) {
  const float* x      = (const float*)d_in[0];
  const int*   wq     = (const int*)d_in[1];
  const float* wscale = (const float*)d_in[2];
  const float* wbias  = (const float*)d_in[3];
  float* out = (float*)d_out;

  const size_t xb_bytes = (size_t)M_TOT * K_DIM * 2;   // 32 MB
  const size_t wb_bytes = (size_t)N_DIM * K_DIM * 2;   // 128 MB
  if (ws_size < xb_bytes + wb_bytes) return;

  ushort* xb = (ushort*)d_ws;
  ushort* wb = (ushort*)((char*)d_ws + xb_bytes);

  cvt_f32_bf16_k<<<2048, 256, 0, stream>>>((const float4*)x, (ushort4*)xb,
                                           (M_TOT * K_DIM) / 4);
  cvt_i32_bf16_k<<<2048, 256, 0, stream>>>((const int4*)wq, (ushort4*)wb,
                                           (N_DIM * K_DIM) / 4);

  const int grid = (M_TOT / 256) * (N_DIM / 256);  // 16 * 64 = 1024
  gemm_8phase<<<grid, 512, 0, stream>>>(xb, wb, wscale, wbias, out);
}

// Round 6
// 386.228 us; speedup vs baseline: 1.7901x; 1.7901x over previous
//
#include <hip/hip_runtime.h>
#include <stdint.h>

// Problem constants
#define M_TOT 4096   // 2 * 2048
#define K_DIM 4096   // IN_FEATURES
#define N_DIM 16384  // OUT_FEATURES

typedef __attribute__((ext_vector_type(4))) int i32x4;  // i8 MFMA operands / acc

__device__ __forceinline__ int pack4(float a, float b, float c, float d, float inv) {
  int q0 = __float2int_rn(a * inv) & 255;
  int q1 = __float2int_rn(b * inv) & 255;
  int q2 = __float2int_rn(c * inv) & 255;
  int q3 = __float2int_rn(d * inv);
  return q0 | (q1 << 8) | (q2 << 16) | (q3 << 24);
}

// x: per-row absmax int8 quantization. One 256-thread block per row.
__global__ __launch_bounds__(256)
void quant_x_k(const float* __restrict__ x, int4* __restrict__ xq,
               float* __restrict__ rowScale) {
  const int row = blockIdx.x;
  const int tid = threadIdx.x;
  const float* xr = x + (size_t)row * K_DIM + tid * 16;
  float4 v[4];
  float m = 0.f;
#pragma unroll
  for (int i = 0; i < 4; ++i) {
    v[i] = *(const float4*)(xr + i * 4);
    m = fmaxf(m, fmaxf(fmaxf(fabsf(v[i].x), fabsf(v[i].y)),
                       fmaxf(fabsf(v[i].z), fabsf(v[i].w))));
  }
#pragma unroll
  for (int off = 32; off > 0; off >>= 1)
    m = fmaxf(m, __shfl_xor(m, off));
  __shared__ float wmx[4];
  if ((tid & 63) == 0) wmx[tid >> 6] = m;
  __syncthreads();
  m = fmaxf(fmaxf(wmx[0], wmx[1]), fmaxf(wmx[2], wmx[3]));
  m = fmaxf(m, 1e-20f);
  if (tid == 0) rowScale[row] = m / 127.f;
  const float inv = 127.f / m;
  int4 o;
  o.x = pack4(v[0].x, v[0].y, v[0].z, v[0].w, inv);
  o.y = pack4(v[1].x, v[1].y, v[1].z, v[1].w, inv);
  o.z = pack4(v[2].x, v[2].y, v[2].z, v[2].w, inv);
  o.w = pack4(v[3].x, v[3].y, v[3].z, v[3].w, inv);
  xq[((size_t)row * K_DIM >> 4) + tid] = o;
}

// weights: i32 in [-7,7] -> i8 (exact). 16 elems/thread/iter.
__global__ void cvt_w_k(const int4* __restrict__ src, int4* __restrict__ dst, int n16) {
  int stride = gridDim.x * blockDim.x;
  for (int i = blockIdx.x * blockDim.x + threadIdx.x; i < n16; i += stride) {
    int4 o;
#pragma unroll
    for (int j = 0; j < 4; ++j) {
      int4 v = src[i * 4 + j];
      int p = (v.x & 255) | ((v.y & 255) << 8) | ((v.z & 255) << 16) | (v.w << 24);
      (&o.x)[j] = p;
    }
    dst[i] = o;
  }
}

__device__ __forceinline__ void gload16(const void* g, void* l) {
  __builtin_amdgcn_global_load_lds(
      (__attribute__((address_space(1))) void*)(g),
      (__attribute__((address_space(3))) void*)(l),
      16, 0, 0);
}

// XOR-swizzle involution on byte offsets within a 16KB block ([256 rows][64 B],
// 64B rows -- byte-identical to the round-2 bf16 layout). Verified round 2:
// SQ_LDS_BANK_CONFLICT == 0 with this exact read pattern.
#define SWZ(o) ((o) ^ ((((o) >> 7) & 7) << 4))

#define MFMA_I8(a, b, c) __builtin_amdgcn_mfma_i32_16x16x64_i8(a, b, c, 0, 0, 0)

// 256x256 tile, K-tile = 128 i8 (2 slices of 64), 8 waves (2M x 4N),
// 4 phases/K-tile, counted vmcnt(4), setprio, XOR-swizzled LDS.
// Byte-for-byte the round-2 schedule (proven fastest), dtype swapped to i8.
// LDS (bytes): buf b at b*65536; A slice s at +s*16384; B slice s at +32768+s*16384.
__global__ __launch_bounds__(512, 2)
void gemm_i8(const char* __restrict__ A, const char* __restrict__ W,
             const float* __restrict__ rowScale, const float* __restrict__ scale,
             const float* __restrict__ bias, float* __restrict__ C) {
  __shared__ __align__(16) char lds[131072];  // 128 KiB
  char* lbase = lds;

  const int tid  = threadIdx.x;
  const int lane = tid & 63;
  const int wave = tid >> 6;
  const int wm   = wave >> 2;  // 0..1
  const int wn   = wave & 3;   // 0..3
  const int r    = lane & 15;
  const int kq16 = (lane >> 4) << 4;  // kq*16 bytes

  // round-2 XCD-bijective swizzle (proven fastest; nwg=1024 divisible by 8)
  const int nwg  = gridDim.x;
  const int bid  = blockIdx.x;
  const int wgid = (bid & 7) * (nwg >> 3) + (bid >> 3);
  const int tm   = wgid >> 6;   // 64 tn-tiles per row
  const int tn   = wgid & 63;
  const int row0 = tm * 256;
  const int col0 = tn * 256;

  // Staging: per-thread global coords; linear LDS dest off holds logical SWZ(off).
  // i8: byte offset within a 64B row == element offset.
  int s_row0, s_col0, s_row1, s_col1;
  {
    int l0 = SWZ(tid * 16);
    int l1 = SWZ(8192 + tid * 16);
    s_row0 = l0 >> 6; s_col0 = l0 & 63;
    s_row1 = l1 >> 6; s_col1 = l1 & 63;
  }

  auto STAGE = [&](const char* G, int rb, int kb, int blkB) {
    gload16(G + (size_t)(rb + s_row0) * K_DIM + kb + s_col0,
            lbase + blkB + (wave << 10));
    gload16(G + (size_t)(rb + s_row1) * K_DIM + kb + s_col1,
            lbase + blkB + 8192 + (wave << 10));
  };

  i32x4 acc[8][4];
#pragma unroll
  for (int i = 0; i < 8; ++i)
#pragma unroll
    for (int j = 0; j < 4; ++j)
      acc[i][j] = (i32x4){0, 0, 0, 0};

  // Prologue: tile0 all 4 blocks + tile1 slice-0 blocks
  STAGE(A, row0, 0,   0);
  STAGE(W, col0, 0,   32768);
  STAGE(A, row0, 64,  16384);
  STAGE(W, col0, 64,  49152);
  STAGE(A, row0, 128, 65536);
  STAGE(W, col0, 128, 98304);
  asm volatile("s_waitcnt vmcnt(4)" ::: "memory");  // T0 resident, T1-s0 in flight
  __builtin_amdgcn_s_barrier();

  i32x4 a[4], b[4];

  for (int t = 0; t < 32; ++t) {
    const int cur  = t & 1;
    const int curB = cur << 16;
    const int nxtB = (cur ^ 1) << 16;
    const int kb1  = ((t + 1 < 32) ? t + 1 : 31) * 128;  // clamp keeps vmcnt uniform
    const int kb2  = ((t + 2 < 32) ? t + 2 : 31) * 128;

    // ---- P1: slice0 x m-half0 ----
#pragma unroll
    for (int q = 0; q < 4; ++q)
      a[q] = *(const i32x4*)(lbase + curB + SWZ(((wm * 128 + q * 16 + r) << 6) + kq16));
#pragma unroll
    for (int q = 0; q < 4; ++q)
      b[q] = *(const i32x4*)(lbase + curB + 32768 + SWZ(((wn * 64 + q * 16 + r) << 6) + kq16));
    STAGE(A, row0, kb1 + 64, nxtB + 16384);  // T(t+1) A s1
    __builtin_amdgcn_s_barrier();
    __builtin_amdgcn_s_setprio(1);
#pragma unroll
    for (int mi = 0; mi < 4; ++mi)
#pragma unroll
      for (int ni = 0; ni < 4; ++ni)
        acc[mi][ni] = MFMA_I8(a[mi], b[ni], acc[mi][ni]);
    __builtin_amdgcn_s_setprio(0);
    __builtin_amdgcn_s_barrier();

    // ---- P2: slice0 x m-half1 (reuse b) ----
#pragma unroll
    for (int q = 0; q < 4; ++q)
      a[q] = *(const i32x4*)(lbase + curB + SWZ(((wm * 128 + (4 + q) * 16 + r) << 6) + kq16));
    STAGE(W, col0, kb1 + 64, nxtB + 49152);  // T(t+1) B s1
    __builtin_amdgcn_s_barrier();
    __builtin_amdgcn_s_setprio(1);
#pragma unroll
    for (int mi = 0; mi < 4; ++mi)
#pragma unroll
      for (int ni = 0; ni < 4; ++ni)
        acc[4 + mi][ni] = MFMA_I8(a[mi], b[ni], acc[4 + mi][ni]);
    __builtin_amdgcn_s_setprio(0);
    __builtin_amdgcn_s_barrier();

    // ---- P3: slice1 x m-half0 ----
#pragma unroll
    for (int q = 0; q < 4; ++q)
      a[q] = *(const i32x4*)(lbase + curB + 16384 + SWZ(((wm * 128 + q * 16 + r) << 6) + kq16));
#pragma unroll
    for (int q = 0; q < 4; ++q)
      b[q] = *(const i32x4*)(lbase + curB + 49152 + SWZ(((wn * 64 + q * 16 + r) << 6) + kq16));
    STAGE(A, row0, kb2, curB);  // T(t+2) A s0 -> dead region
    __builtin_amdgcn_s_barrier();
    __builtin_amdgcn_s_setprio(1);
#pragma unroll
    for (int mi = 0; mi < 4; ++mi)
#pragma unroll
      for (int ni = 0; ni < 4; ++ni)
        acc[mi][ni] = MFMA_I8(a[mi], b[ni], acc[mi][ni]);
    __builtin_amdgcn_s_setprio(0);
    __builtin_amdgcn_s_barrier();

    // ---- P4: slice1 x m-half1 (reuse b) ----
#pragma unroll
    for (int q = 0; q < 4; ++q)
      a[q] = *(const i32x4*)(lbase + curB + 16384 + SWZ(((wm * 128 + (4 + q) * 16 + r) << 6) + kq16));
    STAGE(W, col0, kb2, curB + 32768);  // T(t+2) B s0 -> dead region
    __builtin_amdgcn_s_barrier();
    __builtin_amdgcn_s_setprio(1);
#pragma unroll
    for (int mi = 0; mi < 4; ++mi)
#pragma unroll
      for (int ni = 0; ni < 4; ++ni)
        acc[4 + mi][ni] = MFMA_I8(a[mi], b[ni], acc[4 + mi][ni]);
    __builtin_amdgcn_s_setprio(0);
    // counted wait: <=4 outstanding (= T(t+2) s0); T(t+1) fully landed
    asm volatile("s_waitcnt vmcnt(4)" ::: "memory");
    __builtin_amdgcn_s_barrier();
  }

  asm volatile("s_waitcnt vmcnt(0)" ::: "memory");

  // Epilogue: C/D layout col=lane&15, row=(lane>>4)*4+reg (verified rounds 1-2;
  // dtype-independent per m121-m128). out = acc * (rowScale * colScale) + bias.
  const int kq = kq16 >> 4;
  float rsv[8][4];
#pragma unroll
  for (int mi = 0; mi < 8; ++mi) {
    const int rowb = row0 + wm * 128 + mi * 16 + kq * 4;
#pragma unroll
    for (int q = 0; q < 4; ++q)
      rsv[mi][q] = rowScale[rowb + q];
  }
#pragma unroll
  for (int ni = 0; ni < 4; ++ni) {
    const int col = col0 + wn * 64 + ni * 16 + r;
    const float sc = scale[col];
    const float bv = bias[col];
#pragma unroll
    for (int mi = 0; mi < 8; ++mi) {
      const int rowb = row0 + wm * 128 + mi * 16 + kq * 4;
#pragma unroll
      for (int q = 0; q < 4; ++q)
        C[(size_t)(rowb + q) * N_DIM + col] =
            (float)acc[mi][ni][q] * (rsv[mi][q] * sc) + bv;
    }
  }
}

extern "C" void kernel_launch(void* const* d_in, const int* in_sizes, int n_in,
                              void* d_out, int out_size, void* d_ws, size_t ws_size,
                              hipStream_t stream) {
  const float* x      = (const float*)d_in[0];
  const int*   wq     = (const int*)d_in[1];
  const float* wscale = (const float*)d_in[2];
  const float* wbias  = (const float*)d_in[3];
  float* out = (float*)d_out;

  const size_t xq_bytes = (size_t)M_TOT * K_DIM;       // 16 MB
  const size_t wq_bytes = (size_t)N_DIM * K_DIM;       // 64 MB
  const size_t rs_bytes = (size_t)M_TOT * 4;           // 16 KB
  if (ws_size < xq_bytes + wq_bytes + rs_bytes) return;

  char*  xq8 = (char*)d_ws;
  char*  wq8 = (char*)d_ws + xq_bytes;
  float* rs  = (float*)((char*)d_ws + xq_bytes + wq_bytes);

  quant_x_k<<<M_TOT, 256, 0, stream>>>(x, (int4*)xq8, rs);
  cvt_w_k<<<2048, 256, 0, stream>>>((const int4*)wq, (int4*)wq8,
                                    (N_DIM * K_DIM) / 16);

  const int grid = (M_TOT / 256) * (N_DIM / 256);  // 16 * 64 = 1024
  gemm_i8<<<grid, 512, 0, stream>>>(xq8, wq8, rs, wscale, wbias, out);
}

// Round 7
// 385.368 us; speedup vs baseline: 1.7941x; 1.0022x over previous
//
#include <hip/hip_runtime.h>
#include <stdint.h>

// Problem constants
#define M_TOT 4096   // 2 * 2048
#define K_DIM 4096   // IN_FEATURES
#define N_DIM 16384  // OUT_FEATURES

typedef __attribute__((ext_vector_type(4))) int i32x4;  // i8 MFMA operands / acc

__device__ __forceinline__ int pack4(float a, float b, float c, float d, float inv) {
  int q0 = __float2int_rn(a * inv) & 255;
  int q1 = __float2int_rn(b * inv) & 255;
  int q2 = __float2int_rn(c * inv) & 255;
  int q3 = __float2int_rn(d * inv);
  return q0 | (q1 << 8) | (q2 << 16) | (q3 << 24);
}

// x: per-row absmax int8 quantization. One 256-thread block per row.
__global__ __launch_bounds__(256)
void quant_x_k(const float* __restrict__ x, int4* __restrict__ xq,
               float* __restrict__ rowScale) {
  const int row = blockIdx.x;
  const int tid = threadIdx.x;
  const float* xr = x + (size_t)row * K_DIM + tid * 16;
  float4 v[4];
  float m = 0.f;
#pragma unroll
  for (int i = 0; i < 4; ++i) {
    v[i] = *(const float4*)(xr + i * 4);
    m = fmaxf(m, fmaxf(fmaxf(fabsf(v[i].x), fabsf(v[i].y)),
                       fmaxf(fabsf(v[i].z), fabsf(v[i].w))));
  }
#pragma unroll
  for (int off = 32; off > 0; off >>= 1)
    m = fmaxf(m, __shfl_xor(m, off));
  __shared__ float wmx[4];
  if ((tid & 63) == 0) wmx[tid >> 6] = m;
  __syncthreads();
  m = fmaxf(fmaxf(wmx[0], wmx[1]), fmaxf(wmx[2], wmx[3]));
  m = fmaxf(m, 1e-20f);
  if (tid == 0) rowScale[row] = m / 127.f;
  const float inv = 127.f / m;
  int4 o;
  o.x = pack4(v[0].x, v[0].y, v[0].z, v[0].w, inv);
  o.y = pack4(v[1].x, v[1].y, v[1].z, v[1].w, inv);
  o.z = pack4(v[2].x, v[2].y, v[2].z, v[2].w, inv);
  o.w = pack4(v[3].x, v[3].y, v[3].z, v[3].w, inv);
  xq[((size_t)row * K_DIM >> 4) + tid] = o;
}

// weights: i32 in [-7,7] -> i8 (exact). 16 elems/thread/iter.
__global__ void cvt_w_k(const int4* __restrict__ src, int4* __restrict__ dst, int n16) {
  int stride = gridDim.x * blockDim.x;
  for (int i = blockIdx.x * blockDim.x + threadIdx.x; i < n16; i += stride) {
    int4 o;
#pragma unroll
    for (int j = 0; j < 4; ++j) {
      int4 v = src[i * 4 + j];
      int p = (v.x & 255) | ((v.y & 255) << 8) | ((v.z & 255) << 16) | (v.w << 24);
      (&o.x)[j] = p;
    }
    dst[i] = o;
  }
}

__device__ __forceinline__ void gload16(const void* g, void* l) {
  __builtin_amdgcn_global_load_lds(
      (__attribute__((address_space(1))) void*)(g),
      (__attribute__((address_space(3))) void*)(l),
      16, 0, 0);
}

// XOR-swizzle involution on byte offsets within a 16KB block ([256 rows][64 B]).
// Verified rounds 2/6: SQ_LDS_BANK_CONFLICT == 0 with this read pattern.
#define SWZ(o) ((o) ^ ((((o) >> 7) & 7) << 4))

#define MFMA_I8(a, b, c) __builtin_amdgcn_mfma_i32_16x16x64_i8(a, b, c, 0, 0, 0)

// 256x256 tile, K-tile = 128 i8 (2 slices of 64), 8 waves (2M x 4N),
// 4 phases/K-tile, ONE barrier per phase (end-of-phase), counted vmcnt(4),
// setprio, XOR-swizzled LDS.
// Safety (vs round-6's 2 barriers/phase): each STAGE's dest region had its
// last reader >=1 barrier earlier (P3->curA-s0 read last in P2; P4->curB-s0
// read last in P1; P1/P2->nxt s1 read last in prev tile's P3/P4). Read
// validity unchanged: s1 slices drained by this tile's vmcnt(4); s0 slices
// staged 2 tiles ahead, drained by the NEXT tile's vmcnt(4).
// LDS (bytes): buf b at b*65536; A slice s at +s*16384; B slice s at +32768+s*16384.
__global__ __launch_bounds__(512, 2)
void gemm_i8(const char* __restrict__ A, const char* __restrict__ W,
             const float* __restrict__ rowScale, const float* __restrict__ scale,
             const float* __restrict__ bias, float* __restrict__ C) {
  __shared__ __align__(16) char lds[131072];  // 128 KiB
  char* lbase = lds;

  const int tid  = threadIdx.x;
  const int lane = tid & 63;
  const int wave = tid >> 6;
  const int wm   = wave >> 2;  // 0..1
  const int wn   = wave & 3;   // 0..3
  const int r    = lane & 15;
  const int kq16 = (lane >> 4) << 4;  // kq*16 bytes

  // round-2 XCD-bijective swizzle (nwg=1024 divisible by 8)
  const int nwg  = gridDim.x;
  const int bid  = blockIdx.x;
  const int wgid = (bid & 7) * (nwg >> 3) + (bid >> 3);
  const int tm   = wgid >> 6;   // 64 tn-tiles per row
  const int tn   = wgid & 63;
  const int row0 = tm * 256;
  const int col0 = tn * 256;

  // Staging: per-thread global coords; linear LDS dest off holds logical SWZ(off).
  int s_row0, s_col0, s_row1, s_col1;
  {
    int l0 = SWZ(tid * 16);
    int l1 = SWZ(8192 + tid * 16);
    s_row0 = l0 >> 6; s_col0 = l0 & 63;
    s_row1 = l1 >> 6; s_col1 = l1 & 63;
  }

  auto STAGE = [&](const char* G, int rb, int kb, int blkB) {
    gload16(G + (size_t)(rb + s_row0) * K_DIM + kb + s_col0,
            lbase + blkB + (wave << 10));
    gload16(G + (size_t)(rb + s_row1) * K_DIM + kb + s_col1,
            lbase + blkB + 8192 + (wave << 10));
  };

  i32x4 acc[8][4];
#pragma unroll
  for (int i = 0; i < 8; ++i)
#pragma unroll
    for (int j = 0; j < 4; ++j)
      acc[i][j] = (i32x4){0, 0, 0, 0};

  // Prologue: tile0 all 4 blocks + tile1 slice-0 blocks
  STAGE(A, row0, 0,   0);
  STAGE(W, col0, 0,   32768);
  STAGE(A, row0, 64,  16384);
  STAGE(W, col0, 64,  49152);
  STAGE(A, row0, 128, 65536);
  STAGE(W, col0, 128, 98304);
  asm volatile("s_waitcnt vmcnt(4)" ::: "memory");  // T0 resident, T1-s0 in flight
  __builtin_amdgcn_s_barrier();

  i32x4 a[4], b[4];

  for (int t = 0; t < 32; ++t) {
    const int cur  = t & 1;
    const int curB = cur << 16;
    const int nxtB = (cur ^ 1) << 16;
    const int kb1  = ((t + 1 < 32) ? t + 1 : 31) * 128;  // clamp keeps vmcnt uniform
    const int kb2  = ((t + 2 < 32) ? t + 2 : 31) * 128;

    // ---- P1: slice0 x m-half0 ----
#pragma unroll
    for (int q = 0; q < 4; ++q)
      a[q] = *(const i32x4*)(lbase + curB + SWZ(((wm * 128 + q * 16 + r) << 6) + kq16));
#pragma unroll
    for (int q = 0; q < 4; ++q)
      b[q] = *(const i32x4*)(lbase + curB + 32768 + SWZ(((wn * 64 + q * 16 + r) << 6) + kq16));
    STAGE(A, row0, kb1 + 64, nxtB + 16384);  // T(t+1) A s1
    __builtin_amdgcn_s_setprio(1);
#pragma unroll
    for (int mi = 0; mi < 4; ++mi)
#pragma unroll
      for (int ni = 0; ni < 4; ++ni)
        acc[mi][ni] = MFMA_I8(a[mi], b[ni], acc[mi][ni]);
    __builtin_amdgcn_s_setprio(0);
    __builtin_amdgcn_s_barrier();

    // ---- P2: slice0 x m-half1 (reuse b) ----
#pragma unroll
    for (int q = 0; q < 4; ++q)
      a[q] = *(const i32x4*)(lbase + curB + SWZ(((wm * 128 + (4 + q) * 16 + r) << 6) + kq16));
    STAGE(W, col0, kb1 + 64, nxtB + 49152);  // T(t+1) B s1
    __builtin_amdgcn_s_setprio(1);
#pragma unroll
    for (int mi = 0; mi < 4; ++mi)
#pragma unroll
      for (int ni = 0; ni < 4; ++ni)
        acc[4 + mi][ni] = MFMA_I8(a[mi], b[ni], acc[4 + mi][ni]);
    __builtin_amdgcn_s_setprio(0);
    __builtin_amdgcn_s_barrier();

    // ---- P3: slice1 x m-half0 ----
#pragma unroll
    for (int q = 0; q < 4; ++q)
      a[q] = *(const i32x4*)(lbase + curB + 16384 + SWZ(((wm * 128 + q * 16 + r) << 6) + kq16));
#pragma unroll
    for (int q = 0; q < 4; ++q)
      b[q] = *(const i32x4*)(lbase + curB + 49152 + SWZ(((wn * 64 + q * 16 + r) << 6) + kq16));
    STAGE(A, row0, kb2, curB);  // T(t+2) A s0 -> region last read in P2 (1 barrier ago)
    __builtin_amdgcn_s_setprio(1);
#pragma unroll
    for (int mi = 0; mi < 4; ++mi)
#pragma unroll
      for (int ni = 0; ni < 4; ++ni)
        acc[mi][ni] = MFMA_I8(a[mi], b[ni], acc[mi][ni]);
    __builtin_amdgcn_s_setprio(0);
    __builtin_amdgcn_s_barrier();

    // ---- P4: slice1 x m-half1 (reuse b) ----
#pragma unroll
    for (int q = 0; q < 4; ++q)
      a[q] = *(const i32x4*)(lbase + curB + 16384 + SWZ(((wm * 128 + (4 + q) * 16 + r) << 6) + kq16));
    STAGE(W, col0, kb2, curB + 32768);  // T(t+2) B s0 -> last read in P1 (2+ barriers ago)
    __builtin_amdgcn_s_setprio(1);
#pragma unroll
    for (int mi = 0; mi < 4; ++mi)
#pragma unroll
      for (int ni = 0; ni < 4; ++ni)
        acc[4 + mi][ni] = MFMA_I8(a[mi], b[ni], acc[4 + mi][ni]);
    __builtin_amdgcn_s_setprio(0);
    // counted wait: <=4 outstanding (= T(t+2) s0); T(t+1) s1 fully landed
    asm volatile("s_waitcnt vmcnt(4)" ::: "memory");
    __builtin_amdgcn_s_barrier();
  }

  asm volatile("s_waitcnt vmcnt(0)" ::: "memory");

  // Epilogue: C/D layout col=lane&15, row=(lane>>4)*4+reg (verified rounds 1-6).
  const int kq = kq16 >> 4;
  float rsv[8][4];
#pragma unroll
  for (int mi = 0; mi < 8; ++mi) {
    const int rowb = row0 + wm * 128 + mi * 16 + kq * 4;
#pragma unroll
    for (int q = 0; q < 4; ++q)
      rsv[mi][q] = rowScale[rowb + q];
  }
#pragma unroll
  for (int ni = 0; ni < 4; ++ni) {
    const int col = col0 + wn * 64 + ni * 16 + r;
    const float sc = scale[col];
    const float bv = bias[col];
#pragma unroll
    for (int mi = 0; mi < 8; ++mi) {
      const int rowb = row0 + wm * 128 + mi * 16 + kq * 4;
#pragma unroll
      for (int q = 0; q < 4; ++q)
        C[(size_t)(rowb + q) * N_DIM + col] =
            (float)acc[mi][ni][q] * (rsv[mi][q] * sc) + bv;
    }
  }
}

extern "C" void kernel_launch(void* const* d_in, const int* in_sizes, int n_in,
                              void* d_out, int out_size, void* d_ws, size_t ws_size,
                              hipStream_t stream) {
  const float* x      = (const float*)d_in[0];
  const int*   wq     = (const int*)d_in[1];
  const float* wscale = (const float*)d_in[2];
  const float* wbias  = (const float*)d_in[3];
  float* out = (float*)d_out;

  const size_t xq_bytes = (size_t)M_TOT * K_DIM;       // 16 MB
  const size_t wq_bytes = (size_t)N_DIM * K_DIM;       // 64 MB
  const size_t rs_bytes = (size_t)M_TOT * 4;           // 16 KB
  if (ws_size < xq_bytes + wq_bytes + rs_bytes) return;

  char*  xq8 = (char*)d_ws;
  char*  wq8 = (char*)d_ws + xq_bytes;
  float* rs  = (float*)((char*)d_ws + xq_bytes + wq_bytes);

  quant_x_k<<<M_TOT, 256, 0, stream>>>(x, (int4*)xq8, rs);
  cvt_w_k<<<2048, 256, 0, stream>>>((const int4*)wq, (int4*)wq8,
                                    (N_DIM * K_DIM) / 16);

  const int grid = (M_TOT / 256) * (N_DIM / 256);  // 16 * 64 = 1024
  gemm_i8<<<grid, 512, 0, stream>>>(xq8, wq8, rs, wscale, wbias, out);
}

// Round 8
// 381.670 us; speedup vs baseline: 1.8115x; 1.0097x over previous
//
#include <hip/hip_runtime.h>
#include <stdint.h>

// Problem constants
#define M_TOT 4096   // 2 * 2048
#define K_DIM 4096   // IN_FEATURES
#define N_DIM 16384  // OUT_FEATURES

typedef __attribute__((ext_vector_type(4))) int i32x4;  // i8 MFMA operands / acc

__device__ __forceinline__ int pack4(float a, float b, float c, float d, float inv) {
  int q0 = __float2int_rn(a * inv) & 255;
  int q1 = __float2int_rn(b * inv) & 255;
  int q2 = __float2int_rn(c * inv) & 255;
  int q3 = __float2int_rn(d * inv);
  return q0 | (q1 << 8) | (q2 << 16) | (q3 << 24);
}

// x: per-row absmax int8 quantization. One 256-thread block per row.
__global__ __launch_bounds__(256)
void quant_x_k(const float* __restrict__ x, int4* __restrict__ xq,
               float* __restrict__ rowScale) {
  const int row = blockIdx.x;
  const int tid = threadIdx.x;
  const float* xr = x + (size_t)row * K_DIM + tid * 16;
  float4 v[4];
  float m = 0.f;
#pragma unroll
  for (int i = 0; i < 4; ++i) {
    v[i] = *(const float4*)(xr + i * 4);
    m = fmaxf(m, fmaxf(fmaxf(fabsf(v[i].x), fabsf(v[i].y)),
                       fmaxf(fabsf(v[i].z), fabsf(v[i].w))));
  }
#pragma unroll
  for (int off = 32; off > 0; off >>= 1)
    m = fmaxf(m, __shfl_xor(m, off));
  __shared__ float wmx[4];
  if ((tid & 63) == 0) wmx[tid >> 6] = m;
  __syncthreads();
  m = fmaxf(fmaxf(wmx[0], wmx[1]), fmaxf(wmx[2], wmx[3]));
  m = fmaxf(m, 1e-20f);
  if (tid == 0) rowScale[row] = m / 127.f;
  const float inv = 127.f / m;
  int4 o;
  o.x = pack4(v[0].x, v[0].y, v[0].z, v[0].w, inv);
  o.y = pack4(v[1].x, v[1].y, v[1].z, v[1].w, inv);
  o.z = pack4(v[2].x, v[2].y, v[2].z, v[2].w, inv);
  o.w = pack4(v[3].x, v[3].y, v[3].z, v[3].w, inv);
  xq[((size_t)row * K_DIM >> 4) + tid] = o;
}

// weights: i32 in [-7,7] -> i8 (exact). 16 elems/thread/iter.
__global__ void cvt_w_k(const int4* __restrict__ src, int4* __restrict__ dst, int n16) {
  int stride = gridDim.x * blockDim.x;
  for (int i = blockIdx.x * blockDim.x + threadIdx.x; i < n16; i += stride) {
    int4 o;
#pragma unroll
    for (int j = 0; j < 4; ++j) {
      int4 v = src[i * 4 + j];
      int p = (v.x & 255) | ((v.y & 255) << 8) | ((v.z & 255) << 16) | (v.w << 24);
      (&o.x)[j] = p;
    }
    dst[i] = o;
  }
}

__device__ __forceinline__ void gload16(const void* g, void* l) {
  __builtin_amdgcn_global_load_lds(
      (__attribute__((address_space(1))) void*)(g),
      (__attribute__((address_space(3))) void*)(l),
      16, 0, 0);
}

// XOR-swizzle involution on byte offsets within a 32KB block ([256 rows][128 B]).
// row = o>>7; XOR bits 4-6 with row&7 (bits 7-9 untouched -> involution).
// Fragment read: 16 lanes share a byte-col, consecutive rows -> slot = col^row&7
// -> 8 slots x 2 lanes = 2-way (free, m136). Same family as the round-2/6
// verified swizzle (SQ_LDS_BANK_CONFLICT == 0).
#define SWZ(o) ((o) ^ ((((o) >> 7) & 7) << 4))

#define MFMA_I8(a, b, c) __builtin_amdgcn_mfma_i32_16x16x64_i8(a, b, c, 0, 0, 0)

// 256x256 tile, BK=128 (2 k-slices of 64), 8 waves (2M x 4N).
// K-tile-granular double buffer: per tile, issue ALL 8 prefetch gload16s for
// t+1 into buf^1, then 24 ds_reads + 64 MFMAs from buf with NO intra-tile
// barriers (waves desync -> cross-wave read/MFMA overlap), then one
// vmcnt(0)+barrier per tile.
// Race audit: reads of buf[cur] certified by prev tile's vmcnt(0)+barrier;
// stage into buf[cur^1] issued after the barrier following its last reads
// (consumed via lgkmcnt before that tile's MFMAs, which precede the barrier).
// LDS (bytes): buf b at b*65536; A at +0 (32KB), B at +32768 (32KB).
__global__ __launch_bounds__(512, 2)
void gemm_i8(const char* __restrict__ A, const char* __restrict__ W,
             const float* __restrict__ rowScale, const float* __restrict__ scale,
             const float* __restrict__ bias, float* __restrict__ C) {
  __shared__ __align__(16) char lds[131072];  // 128 KiB
  char* lbase = lds;

  const int tid  = threadIdx.x;
  const int lane = tid & 63;
  const int wave = tid >> 6;
  const int wm   = wave >> 2;  // 0..1
  const int wn   = wave & 3;   // 0..3
  const int r    = lane & 15;
  const int kq16 = (lane >> 4) << 4;  // kq*16 bytes

  // round-2 XCD-bijective swizzle (nwg=1024 divisible by 8)
  const int nwg  = gridDim.x;
  const int bid  = blockIdx.x;
  const int wgid = (bid & 7) * (nwg >> 3) + (bid >> 3);
  const int tm   = wgid >> 6;   // 64 tn-tiles per row
  const int tn   = wgid & 63;
  const int row0 = tm * 256;
  const int col0 = tn * 256;

  // Staging: 4 issues per 32KB block; linear LDS dest off j*8192 + tid*16
  // holds logical SWZ(off) -> pre-swizzled global source coords.
  size_t tOff[4];
#pragma unroll
  for (int j = 0; j < 4; ++j) {
    int l = SWZ(j * 8192 + tid * 16);
    tOff[j] = (size_t)(l >> 7) * K_DIM + (l & 127);
  }
  const int tid16 = tid * 16;

  const char* Arow = A + (size_t)row0 * K_DIM;
  const char* Wrow = W + (size_t)col0 * K_DIM;

  i32x4 acc[8][4];
#pragma unroll
  for (int i = 0; i < 8; ++i)
#pragma unroll
    for (int j = 0; j < 4; ++j)
      acc[i][j] = (i32x4){0, 0, 0, 0};

  // Prologue: stage tile 0 into buf0
#pragma unroll
  for (int j = 0; j < 4; ++j)
    gload16(Arow + tOff[j], lbase + j * 8192 + tid16);
#pragma unroll
  for (int j = 0; j < 4; ++j)
    gload16(Wrow + tOff[j], lbase + 32768 + j * 8192 + tid16);
  asm volatile("s_waitcnt vmcnt(0)" ::: "memory");
  __builtin_amdgcn_s_barrier();

  i32x4 a[4], b[4];

  for (int t = 0; t < 32; ++t) {
    const int curB = (t & 1) << 16;
    const int nxtB = curB ^ 65536;
    const int kb1  = ((t + 1 < 32) ? t + 1 : 31) * 128;  // clamp: dead rewrite of buf^1

    // issue ALL of tile t+1's staging now (full tile of latency to land)
#pragma unroll
    for (int j = 0; j < 4; ++j)
      gload16(Arow + kb1 + tOff[j], lbase + nxtB + j * 8192 + tid16);
#pragma unroll
    for (int j = 0; j < 4; ++j)
      gload16(Wrow + kb1 + tOff[j], lbase + nxtB + 32768 + j * 8192 + tid16);

    // ---- barrier-free compute of tile t: 4 sub-phases ----
    // sub-phase 1: slice0 x m-half0
#pragma unroll
    for (int q = 0; q < 4; ++q)
      a[q] = *(const i32x4*)(lbase + curB + SWZ(((wm * 128 + q * 16 + r) << 7) + kq16));
#pragma unroll
    for (int q = 0; q < 4; ++q)
      b[q] = *(const i32x4*)(lbase + curB + 32768 + SWZ(((wn * 64 + q * 16 + r) << 7) + kq16));
    __builtin_amdgcn_s_setprio(1);
#pragma unroll
    for (int mi = 0; mi < 4; ++mi)
#pragma unroll
      for (int ni = 0; ni < 4; ++ni)
        acc[mi][ni] = MFMA_I8(a[mi], b[ni], acc[mi][ni]);
    __builtin_amdgcn_s_setprio(0);

    // sub-phase 2: slice0 x m-half1 (reuse b)
#pragma unroll
    for (int q = 0; q < 4; ++q)
      a[q] = *(const i32x4*)(lbase + curB + SWZ(((wm * 128 + (4 + q) * 16 + r) << 7) + kq16));
    __builtin_amdgcn_s_setprio(1);
#pragma unroll
    for (int mi = 0; mi < 4; ++mi)
#pragma unroll
      for (int ni = 0; ni < 4; ++ni)
        acc[4 + mi][ni] = MFMA_I8(a[mi], b[ni], acc[4 + mi][ni]);
    __builtin_amdgcn_s_setprio(0);

    // sub-phase 3: slice1 x m-half0
#pragma unroll
    for (int q = 0; q < 4; ++q)
      a[q] = *(const i32x4*)(lbase + curB + SWZ(((wm * 128 + q * 16 + r) << 7) + 64 + kq16));
#pragma unroll
    for (int q = 0; q < 4; ++q)
      b[q] = *(const i32x4*)(lbase + curB + 32768 + SWZ(((wn * 64 + q * 16 + r) << 7) + 64 + kq16));
    __builtin_amdgcn_s_setprio(1);
#pragma unroll
    for (int mi = 0; mi < 4; ++mi)
#pragma unroll
      for (int ni = 0; ni < 4; ++ni)
        acc[mi][ni] = MFMA_I8(a[mi], b[ni], acc[mi][ni]);
    __builtin_amdgcn_s_setprio(0);

    // sub-phase 4: slice1 x m-half1 (reuse b)
#pragma unroll
    for (int q = 0; q < 4; ++q)
      a[q] = *(const i32x4*)(lbase + curB + SWZ(((wm * 128 + (4 + q) * 16 + r) << 7) + 64 + kq16));
    __builtin_amdgcn_s_setprio(1);
#pragma unroll
    for (int mi = 0; mi < 4; ++mi)
#pragma unroll
      for (int ni = 0; ni < 4; ++ni)
        acc[4 + mi][ni] = MFMA_I8(a[mi], b[ni], acc[4 + mi][ni]);
    __builtin_amdgcn_s_setprio(0);

    // single sync point per tile: t+1's staging landed, all waves done reading
    asm volatile("s_waitcnt vmcnt(0)" ::: "memory");
    __builtin_amdgcn_s_barrier();
  }

  // Epilogue: C/D layout col=lane&15, row=(lane>>4)*4+reg (verified rounds 1-7).
  const int kq = kq16 >> 4;
  float rsv[8][4];
#pragma unroll
  for (int mi = 0; mi < 8; ++mi) {
    const int rowb = row0 + wm * 128 + mi * 16 + kq * 4;
#pragma unroll
    for (int q = 0; q < 4; ++q)
      rsv[mi][q] = rowScale[rowb + q];
  }
#pragma unroll
  for (int ni = 0; ni < 4; ++ni) {
    const int col = col0 + wn * 64 + ni * 16 + r;
    const float sc = scale[col];
    const float bv = bias[col];
#pragma unroll
    for (int mi = 0; mi < 8; ++mi) {
      const int rowb = row0 + wm * 128 + mi * 16 + kq * 4;
#pragma unroll
      for (int q = 0; q < 4; ++q)
        C[(size_t)(rowb + q) * N_DIM + col] =
            (float)acc[mi][ni][q] * (rsv[mi][q] * sc) + bv;
    }
  }
}

extern "C" void kernel_launch(void* const* d_in, const int* in_sizes, int n_in,
                              void* d_out, int out_size, void* d_ws, size_t ws_size,
                              hipStream_t stream) {
  const float* x      = (const float*)d_in[0];
  const int*   wq     = (const int*)d_in[1];
  const float* wscale = (const float*)d_in[2];
  const float* wbias  = (const float*)d_in[3];
  float* out = (float*)d_out;

  const size_t xq_bytes = (size_t)M_TOT * K_DIM;       // 16 MB
  const size_t wq_bytes = (size_t)N_DIM * K_DIM;       // 64 MB
  const size_t rs_bytes = (size_t)M_TOT * 4;           // 16 KB
  if (ws_size < xq_bytes + wq_bytes + rs_bytes) return;

  char*  xq8 = (char*)d_ws;
  char*  wq8 = (char*)d_ws + xq_bytes;
  float* rs  = (float*)((char*)d_ws + xq_bytes + wq_bytes);

  quant_x_k<<<M_TOT, 256, 0, stream>>>(x, (int4*)xq8, rs);
  cvt_w_k<<<2048, 256, 0, stream>>>((const int4*)wq, (int4*)wq8,
                                    (N_DIM * K_DIM) / 16);

  const int grid = (M_TOT / 256) * (N_DIM / 256);  // 16 * 64 = 1024
  gemm_i8<<<grid, 512, 0, stream>>>(xq8, wq8, rs, wscale, wbias, out);
}